// Round 1
// baseline (678.083 us; speedup 1.0000x reference)
//
#include <hip/hip_runtime.h>
#include <hip/hip_bf16.h>

// Problem constants (from reference):
#define DIMV 2048   // dim
#define DIV  2048   // d_inner
#define BV   4
#define TV   4096
#define MV   (BV * TV)   // 16384 rows for both GEMMs
#define GK   2048        // K for both GEMMs
#define NCH  16          // scan chunks
#define CH   256         // scan chunk length (NCH*CH == TV)

typedef __bf16 bf16x8 __attribute__((ext_vector_type(8)));
typedef float  floatx4 __attribute__((ext_vector_type(4)));

__device__ __forceinline__ void gload_lds16(const void* g, void* l) {
    __builtin_amdgcn_global_load_lds((const __attribute__((address_space(1))) void*)g,
                                     (__attribute__((address_space(3))) void*)l,
                                     16, 0, 0);
}

// ---------------- fp32 -> bf16 conversion (vectorized x4) ----------------
__global__ void cvt4_f32_bf16(const float4* __restrict__ in, ushort4* __restrict__ out, int n4) {
    int i = blockIdx.x * blockDim.x + threadIdx.x;
    if (i >= n4) return;
    float4 v = in[i];
    __hip_bfloat16 a = __float2bfloat16(v.x);
    __hip_bfloat16 b = __float2bfloat16(v.y);
    __hip_bfloat16 c = __float2bfloat16(v.z);
    __hip_bfloat16 d = __float2bfloat16(v.w);
    ushort4 o;
    o.x = *(unsigned short*)&a;
    o.y = *(unsigned short*)&b;
    o.z = *(unsigned short*)&c;
    o.w = *(unsigned short*)&d;
    out[i] = o;
}

// ---------------- bf16 GEMM, B-transposed (m97 structure) ----------------
// C[m][n] = sum_k A[m][k] * Bt[n][k]; M=16384, N=2048, K=2048.
// 128x128 tile, BK=32, 4 waves (2x2), each wave 64x64 via 4x4 of 16x16x32 MFMA.
// EPI==1: apply silu, store bf16 to Cb. EPI==0: store fp32 to Cf.
template <int EPI>
__global__ __launch_bounds__(256) void gemm128_bt(const __hip_bfloat16* __restrict__ A,
                                                  const __hip_bfloat16* __restrict__ Bt,
                                                  float* __restrict__ Cf,
                                                  __hip_bfloat16* __restrict__ Cb) {
    __shared__ __align__(16) short As[128 * 32];
    __shared__ __align__(16) short Bs[128 * 32];

    const int tid  = threadIdx.x;
    const int lane = tid & 63;
    const int wave = tid >> 6;
    const int wm   = (wave >> 1) * 64;   // wave M offset in tile
    const int wn   = (wave & 1) * 64;    // wave N offset in tile
    const int lr   = lane & 15;          // row/col within 16-tile
    const int lq   = lane >> 4;          // quad
    const int m0   = blockIdx.y * 128;
    const int n0   = blockIdx.x * 128;

    // Staging map: thread t covers tile bytes [t*16, t*16+16) (rows 0..63),
    // then +4096 bytes (rows 64..127). Tile row = 32 bf16 = 64 B.
    const int srow = tid >> 2;            // 0..63
    const int scol = (tid & 3) * 8;       // bf16 element within row
    const __hip_bfloat16* Ap0 = A  + (size_t)(m0 + srow) * GK + scol;
    const __hip_bfloat16* Ap1 = Ap0 + (size_t)64 * GK;
    const __hip_bfloat16* Bp0 = Bt + (size_t)(n0 + srow) * GK + scol;
    const __hip_bfloat16* Bp1 = Bp0 + (size_t)64 * GK;

    floatx4 acc[4][4];
#pragma unroll
    for (int i = 0; i < 4; ++i)
#pragma unroll
        for (int j = 0; j < 4; ++j) acc[i][j] = 0.f;

    for (int k0 = 0; k0 < GK; k0 += 32) {
        gload_lds16(Ap0 + k0, &As[tid * 8]);
        gload_lds16(Ap1 + k0, &As[2048 + tid * 8]);
        gload_lds16(Bp0 + k0, &Bs[tid * 8]);
        gload_lds16(Bp1 + k0, &Bs[2048 + tid * 8]);
        __syncthreads();

        bf16x8 af[4], bf[4];
#pragma unroll
        for (int i = 0; i < 4; ++i)
            af[i] = *(const bf16x8*)&As[(wm + i * 16 + lr) * 32 + lq * 8];
#pragma unroll
        for (int j = 0; j < 4; ++j)
            bf[j] = *(const bf16x8*)&Bs[(wn + j * 16 + lr) * 32 + lq * 8];
#pragma unroll
        for (int i = 0; i < 4; ++i)
#pragma unroll
            for (int j = 0; j < 4; ++j)
                acc[i][j] = __builtin_amdgcn_mfma_f32_16x16x32_bf16(af[i], bf[j], acc[i][j], 0, 0, 0);
        __syncthreads();
    }

    // Epilogue. C/D layout: col = lane&15, row = quad*4 + reg.
#pragma unroll
    for (int i = 0; i < 4; ++i) {
#pragma unroll
        for (int r = 0; r < 4; ++r) {
            const int row = m0 + wm + i * 16 + lq * 4 + r;
#pragma unroll
            for (int j = 0; j < 4; ++j) {
                const int col = n0 + wn + j * 16 + lr;
                float v = acc[i][j][r];
                if (EPI == 1) {
                    float s = v / (1.f + __expf(-v));   // silu
                    Cb[(size_t)row * DIV + col] = __float2bfloat16(s);
                } else {
                    Cf[(size_t)row * DIMV + col] = v;
                }
            }
        }
    }
}

// ---------------- scan pass 1: per-chunk carries ----------------
// carry[b][c][e] = local scan end (h with zero init) for chunk c.
__global__ __launch_bounds__(256) void scan_carry(const __hip_bfloat16* __restrict__ xp,
                                                  const float* __restrict__ logd,
                                                  const float* __restrict__ bias,
                                                  float* __restrict__ carry) {
    const int e = blockIdx.x * 256 + threadIdx.x;
    const int c = blockIdx.y;
    const int b = blockIdx.z;
    const float dv = 1.f / (1.f + __expf(-logd[e]));
    const float bv = bias[e];
    const __hip_bfloat16* p = xp + ((size_t)(b * TV + c * CH)) * DIV + e;
    float h = 0.f;
#pragma unroll 8
    for (int i = 0; i < CH; ++i) {
        float xv = __bfloat162float(p[(size_t)i * DIV]);
        h = dv * (xv + h) + bv;
    }
    carry[((size_t)b * NCH + c) * DIV + e] = h;
}

// ---------------- scan pass 2: combine carries, emit cell + h_final -------
__global__ __launch_bounds__(256) void scan_apply(const __hip_bfloat16* __restrict__ xp,
                                                  const float* __restrict__ logd,
                                                  const float* __restrict__ bias,
                                                  const float* __restrict__ h0,
                                                  const float* __restrict__ carry,
                                                  __hip_bfloat16* __restrict__ cell,
                                                  float* __restrict__ hfin) {
    const int e = blockIdx.x * 256 + threadIdx.x;
    const int c = blockIdx.y;
    const int b = blockIdx.z;
    const float dv = 1.f / (1.f + __expf(-logd[e]));
    const float bv = bias[e];
    const float dCH = __powf(dv, (float)CH);   // chunk-level decay

    // H = true h at chunk start - 1 (chunk-level recurrence over carries)
    float H = h0[(size_t)b * DIV + e];
    for (int j = 0; j < c; ++j)
        H = dCH * H + carry[((size_t)b * NCH + j) * DIV + e];

    const size_t base = ((size_t)(b * TV + c * CH)) * DIV + e;
    float h = H;
#pragma unroll 8
    for (int i = 0; i < CH; ++i) {
        float xv = __bfloat162float(xp[base + (size_t)i * DIV]);
        h = dv * (xv + h) + bv;
        float cv = h * (h / (1.f + __expf(-h)));   // h * silu(h)
        cell[base + (size_t)i * DIV] = __float2bfloat16(cv);
    }
    if (c == NCH - 1) hfin[(size_t)b * DIV + e] = h;
}

// -------------------------------------------------------------------------
extern "C" void kernel_launch(void* const* d_in, const int* in_sizes, int n_in,
                              void* d_out, int out_size, void* d_ws, size_t ws_size,
                              hipStream_t stream) {
    const float* x     = (const float*)d_in[0];   // [B,T,DIM]
    const float* h0    = (const float*)d_in[1];   // [B,DI]
    const float* W_in  = (const float*)d_in[2];   // [DI,DIM]
    const float* W_out = (const float*)d_in[3];   // [DIM,DI]
    const float* log_d = (const float*)d_in[4];   // [DI]
    const float* bias  = (const float*)d_in[5];   // [DI]

    float* out  = (float*)d_out;                       // [B,T,DIM] fp32
    float* hfin = out + (size_t)BV * TV * DIMV;        // [B,DI] fp32

    // Workspace layout (bytes):
    char* ws = (char*)d_ws;
    __hip_bfloat16* xb    = (__hip_bfloat16*)ws;                          // 64 MiB
    __hip_bfloat16* cellb = xb;                                           // alias: x dead after GEMM1
    __hip_bfloat16* wib   = (__hip_bfloat16*)(ws + 67108864);             // 8 MiB
    __hip_bfloat16* wob   = (__hip_bfloat16*)(ws + 67108864 + 8388608);   // 8 MiB
    __hip_bfloat16* xpb   = (__hip_bfloat16*)(ws + 67108864 + 16777216);  // 64 MiB
    float*          carry = (float*)(ws + 134217728 + 16777216);          // 512 KiB

    // 1) convert inputs to bf16
    {
        int n4 = (BV * TV * DIMV) / 4;   // 8388608
        cvt4_f32_bf16<<<n4 / 256, 256, 0, stream>>>((const float4*)x, (ushort4*)xb, n4);
        int w4 = (DIV * DIMV) / 4;       // 1048576
        cvt4_f32_bf16<<<w4 / 256, 256, 0, stream>>>((const float4*)W_in, (ushort4*)wib, w4);
        cvt4_f32_bf16<<<w4 / 256, 256, 0, stream>>>((const float4*)W_out, (ushort4*)wob, w4);
    }

    // 2) GEMM1: xp = silu(x @ W_in^T), bf16 out
    gemm128_bt<1><<<dim3(DIV / 128, MV / 128), 256, 0, stream>>>(xb, wib, nullptr, xpb);

    // 3) scan: chunk carries, then combine + emit cell (bf16) and h_final
    scan_carry<<<dim3(DIV / 256, NCH, BV), 256, 0, stream>>>(xpb, log_d, bias, carry);
    scan_apply<<<dim3(DIV / 256, NCH, BV), 256, 0, stream>>>(xpb, log_d, bias, h0, carry, cellb, hfin);

    // 4) GEMM2: out = cell @ W_out^T, fp32 out
    gemm128_bt<0><<<dim3(DIMV / 128, MV / 128), 256, 0, stream>>>(cellb, wob, out, nullptr);
}

// Round 2
// 670.152 us; speedup vs baseline: 1.0118x; 1.0118x over previous
//
#include <hip/hip_runtime.h>
#include <hip/hip_bf16.h>

// Problem constants (from reference):
#define DIMV 2048   // dim
#define DIV  2048   // d_inner
#define BV   4
#define TV   4096
#define MV   (BV * TV)   // 16384 rows for both GEMMs
#define GK   2048        // K for both GEMMs
#define NCH  32          // scan chunks
#define CH   128         // scan chunk length (NCH*CH == TV)

typedef __bf16 bf16x8 __attribute__((ext_vector_type(8)));
typedef __bf16 bf16x4 __attribute__((ext_vector_type(4)));
typedef float  floatx4 __attribute__((ext_vector_type(4)));

__device__ __forceinline__ void gload_lds16(const void* g, void* l) {
    __builtin_amdgcn_global_load_lds((const __attribute__((address_space(1))) void*)g,
                                     (__attribute__((address_space(3))) void*)l,
                                     16, 0, 0);
}

// ---------------- fused fp32 -> bf16 conversion (x, W_in, W_out) ----------
// Ranges (in float4 units): x: [0, 8388608), W_in: [8388608, 9437184),
// W_out: [9437184, 10485760).
__global__ __launch_bounds__(256) void cvt_all(const float4* __restrict__ x,
                                               const float4* __restrict__ wi,
                                               const float4* __restrict__ wo,
                                               ushort4* __restrict__ xb,
                                               ushort4* __restrict__ wib,
                                               ushort4* __restrict__ wob) {
    int i = blockIdx.x * 256 + threadIdx.x;
    const float4* src;
    ushort4* dst;
    int off;
    if (i < 8388608)       { src = x;  dst = xb;  off = 0; }
    else if (i < 9437184)  { src = wi; dst = wib; off = 8388608; }
    else                   { src = wo; dst = wob; off = 9437184; }
    float4 v = src[i - off];
    __hip_bfloat16 a = __float2bfloat16(v.x);
    __hip_bfloat16 b = __float2bfloat16(v.y);
    __hip_bfloat16 c = __float2bfloat16(v.z);
    __hip_bfloat16 d = __float2bfloat16(v.w);
    ushort4 o;
    o.x = *(unsigned short*)&a;
    o.y = *(unsigned short*)&b;
    o.z = *(unsigned short*)&c;
    o.w = *(unsigned short*)&d;
    dst[i - off] = o;
}

// ---------------- bf16 GEMM, B-transposed (m97 structure + XCD swizzle) ---
// C[m][n] = sum_k A[m][k] * Bt[n][k]; M=16384, N in {2048}, K=2048.
// 128x128 tile, BK=32, 4 waves (2x2), each wave 64x64 via 4x4 of 16x16x32.
// EPI==1: apply silu, store bf16 to Cb. EPI==0: store fp32 to Cf.
template <int EPI>
__global__ __launch_bounds__(256) void gemm128_bt(const __hip_bfloat16* __restrict__ A,
                                                  const __hip_bfloat16* __restrict__ Bt,
                                                  float* __restrict__ Cf,
                                                  __hip_bfloat16* __restrict__ Cb) {
    __shared__ __align__(16) short As[128 * 32];
    __shared__ __align__(16) short Bs[128 * 32];

    const int tid  = threadIdx.x;
    const int lane = tid & 63;
    const int wave = tid >> 6;
    const int wm   = (wave >> 1) * 64;   // wave M offset in tile
    const int wn   = (wave & 1) * 64;    // wave N offset in tile
    const int lr   = lane & 15;          // row/col within 16-tile
    const int lq   = lane >> 4;          // quad

    // XCD-friendly swizzle: column-major within GROUP_M=8 m-tiles.
    // Consecutive 8 blocks (round-robin -> 8 XCDs) share one B-tile column;
    // each XCD keeps one fixed A-row-tile in its L2 across all 16 n-tiles.
    const int num_n = gridDim.x;                       // 16
    const int p     = blockIdx.y * num_n + blockIdx.x; // linear id
    const int GM    = 8;
    const int grp   = p / (GM * num_n);
    const int rem   = p % (GM * num_n);
    const int m0    = (grp * GM + (rem % GM)) * 128;
    const int n0    = (rem / GM) * 128;

    // Staging map: thread t covers tile bytes [t*16, t*16+16) (rows 0..63),
    // then +4096 bytes (rows 64..127). Tile row = 32 bf16 = 64 B.
    const int srow = tid >> 2;            // 0..63
    const int scol = (tid & 3) * 8;       // bf16 element within row
    const __hip_bfloat16* Ap0 = A  + (size_t)(m0 + srow) * GK + scol;
    const __hip_bfloat16* Ap1 = Ap0 + (size_t)64 * GK;
    const __hip_bfloat16* Bp0 = Bt + (size_t)(n0 + srow) * GK + scol;
    const __hip_bfloat16* Bp1 = Bp0 + (size_t)64 * GK;

    floatx4 acc[4][4];
#pragma unroll
    for (int i = 0; i < 4; ++i)
#pragma unroll
        for (int j = 0; j < 4; ++j) acc[i][j] = 0.f;

    for (int k0 = 0; k0 < GK; k0 += 32) {
        gload_lds16(Ap0 + k0, &As[tid * 8]);
        gload_lds16(Ap1 + k0, &As[2048 + tid * 8]);
        gload_lds16(Bp0 + k0, &Bs[tid * 8]);
        gload_lds16(Bp1 + k0, &Bs[2048 + tid * 8]);
        __syncthreads();

        bf16x8 af[4], bf[4];
#pragma unroll
        for (int i = 0; i < 4; ++i)
            af[i] = *(const bf16x8*)&As[(wm + i * 16 + lr) * 32 + lq * 8];
#pragma unroll
        for (int j = 0; j < 4; ++j)
            bf[j] = *(const bf16x8*)&Bs[(wn + j * 16 + lr) * 32 + lq * 8];
#pragma unroll
        for (int i = 0; i < 4; ++i)
#pragma unroll
            for (int j = 0; j < 4; ++j)
                acc[i][j] = __builtin_amdgcn_mfma_f32_16x16x32_bf16(af[i], bf[j], acc[i][j], 0, 0, 0);
        __syncthreads();
    }

    // Epilogue. C/D layout: col = lane&15, row = quad*4 + reg.
#pragma unroll
    for (int i = 0; i < 4; ++i) {
#pragma unroll
        for (int r = 0; r < 4; ++r) {
            const int row = m0 + wm + i * 16 + lq * 4 + r;
#pragma unroll
            for (int j = 0; j < 4; ++j) {
                const int col = n0 + wn + j * 16 + lr;
                float v = acc[i][j][r];
                if (EPI == 1) {
                    float s = v / (1.f + __expf(-v));   // silu
                    Cb[(size_t)row * DIV + col] = __float2bfloat16(s);
                } else {
                    Cf[(size_t)row * DIMV + col] = v;
                }
            }
        }
    }
}

// ---------------- scan pass 1: per-chunk carries (4 e-channels/thread) ----
// carry[b][c][e] = local scan end (h with zero init) for chunk c.
__global__ __launch_bounds__(256) void scan_carry(const __hip_bfloat16* __restrict__ xp,
                                                  const float* __restrict__ logd,
                                                  const float* __restrict__ bias,
                                                  float* __restrict__ carry) {
    const int eg = blockIdx.x * 256 + threadIdx.x;  // e-group (4 channels)
    const int e0 = eg * 4;
    const int c = blockIdx.y;
    const int b = blockIdx.z;
    const float4 ld = ((const float4*)logd)[eg];
    const float4 bb = ((const float4*)bias)[eg];
    float dv[4] = {1.f / (1.f + __expf(-ld.x)), 1.f / (1.f + __expf(-ld.y)),
                   1.f / (1.f + __expf(-ld.z)), 1.f / (1.f + __expf(-ld.w))};
    float bv[4] = {bb.x, bb.y, bb.z, bb.w};
    const __hip_bfloat16* p = xp + ((size_t)(b * TV + c * CH)) * DIV + e0;
    float h[4] = {0.f, 0.f, 0.f, 0.f};
#pragma unroll 8
    for (int i = 0; i < CH; ++i) {
        bf16x4 v = *(const bf16x4*)(p + (size_t)i * DIV);
#pragma unroll
        for (int j = 0; j < 4; ++j)
            h[j] = dv[j] * ((float)v[j] + h[j]) + bv[j];
    }
    float4 o = {h[0], h[1], h[2], h[3]};
    *(float4*)&carry[((size_t)b * NCH + c) * DIV + e0] = o;
}

// ---------------- scan pass 2: combine carries, emit cell + h_final -------
__global__ __launch_bounds__(256) void scan_apply(const __hip_bfloat16* __restrict__ xp,
                                                  const float* __restrict__ logd,
                                                  const float* __restrict__ bias,
                                                  const float* __restrict__ h0,
                                                  const float* __restrict__ carry,
                                                  __hip_bfloat16* __restrict__ cell,
                                                  float* __restrict__ hfin) {
    const int eg = blockIdx.x * 256 + threadIdx.x;
    const int e0 = eg * 4;
    const int c = blockIdx.y;
    const int b = blockIdx.z;
    const float4 ld = ((const float4*)logd)[eg];
    const float4 bb = ((const float4*)bias)[eg];
    float dv[4] = {1.f / (1.f + __expf(-ld.x)), 1.f / (1.f + __expf(-ld.y)),
                   1.f / (1.f + __expf(-ld.z)), 1.f / (1.f + __expf(-ld.w))};
    float bv[4] = {bb.x, bb.y, bb.z, bb.w};
    float dCH[4];
#pragma unroll
    for (int j = 0; j < 4; ++j) dCH[j] = __powf(dv[j], (float)CH);

    // H = true h at entry to chunk c (chunk-level recurrence over carries)
    float4 H4 = *(const float4*)&h0[(size_t)b * DIV + e0];
    float H[4] = {H4.x, H4.y, H4.z, H4.w};
    for (int j = 0; j < c; ++j) {
        float4 cr = *(const float4*)&carry[((size_t)b * NCH + j) * DIV + e0];
#pragma unroll
        for (int q = 0; q < 4; ++q) H[q] = dCH[q] * H[q] + ((const float*)&cr)[q];
    }

    const size_t base = ((size_t)(b * TV + c * CH)) * DIV + e0;
    float h[4] = {H[0], H[1], H[2], H[3]};
#pragma unroll 4
    for (int i = 0; i < CH; ++i) {
        bf16x4 v = *(const bf16x4*)(xp + base + (size_t)i * DIV);
        ushort4 o;
        unsigned short* op = (unsigned short*)&o;
#pragma unroll
        for (int j = 0; j < 4; ++j) {
            h[j] = dv[j] * ((float)v[j] + h[j]) + bv[j];
            float cv = h[j] * (h[j] / (1.f + __expf(-h[j])));   // h * silu(h)
            __hip_bfloat16 cb = __float2bfloat16(cv);
            op[j] = *(unsigned short*)&cb;
        }
        *(ushort4*)(cell + base + (size_t)i * DIV) = o;
    }
    if (c == NCH - 1) {
        float4 o = {h[0], h[1], h[2], h[3]};
        *(float4*)&hfin[(size_t)b * DIV + e0] = o;
    }
}

// -------------------------------------------------------------------------
extern "C" void kernel_launch(void* const* d_in, const int* in_sizes, int n_in,
                              void* d_out, int out_size, void* d_ws, size_t ws_size,
                              hipStream_t stream) {
    const float* x     = (const float*)d_in[0];   // [B,T,DIM]
    const float* h0    = (const float*)d_in[1];   // [B,DI]
    const float* W_in  = (const float*)d_in[2];   // [DI,DIM]
    const float* W_out = (const float*)d_in[3];   // [DIM,DI]
    const float* log_d = (const float*)d_in[4];   // [DI]
    const float* bias  = (const float*)d_in[5];   // [DI]

    float* out  = (float*)d_out;                       // [B,T,DIM] fp32
    float* hfin = out + (size_t)BV * TV * DIMV;        // [B,DI] fp32

    // Workspace layout (bytes):
    char* ws = (char*)d_ws;
    __hip_bfloat16* xb    = (__hip_bfloat16*)ws;                          // 64 MiB
    __hip_bfloat16* cellb = xb;                                           // alias: x dead after GEMM1
    __hip_bfloat16* wib   = (__hip_bfloat16*)(ws + 67108864);             // 8 MiB
    __hip_bfloat16* wob   = (__hip_bfloat16*)(ws + 67108864 + 8388608);   // 8 MiB
    __hip_bfloat16* xpb   = (__hip_bfloat16*)(ws + 67108864 + 16777216);  // 64 MiB
    float*          carry = (float*)(ws + 134217728 + 16777216);          // 1 MiB

    // 1) convert inputs to bf16 (single fused kernel)
    {
        int n4 = 10485760;   // 8388608 + 1048576 + 1048576 float4s
        cvt_all<<<n4 / 256, 256, 0, stream>>>((const float4*)x, (const float4*)W_in,
                                              (const float4*)W_out,
                                              (ushort4*)xb, (ushort4*)wib, (ushort4*)wob);
    }

    // 2) GEMM1: xp = silu(x @ W_in^T), bf16 out
    gemm128_bt<1><<<dim3(DIV / 128, MV / 128), 256, 0, stream>>>(xb, wib, nullptr, xpb);

    // 3) scan: chunk carries, then combine + emit cell (bf16) and h_final
    scan_carry<<<dim3(DIV / 1024, NCH, BV), 256, 0, stream>>>(xpb, log_d, bias, carry);
    scan_apply<<<dim3(DIV / 1024, NCH, BV), 256, 0, stream>>>(xpb, log_d, bias, h0, carry, cellb, hfin);

    // 4) GEMM2: out = cell @ W_out^T, fp32 out
    gemm128_bt<0><<<dim3(DIMV / 128, MV / 128), 256, 0, stream>>>(cellb, wob, out, nullptr);
}

// Round 3
// 614.676 us; speedup vs baseline: 1.1032x; 1.0903x over previous
//
#include <hip/hip_runtime.h>
#include <hip/hip_bf16.h>

// Problem constants (from reference):
#define DIMV 2048   // dim
#define DIV  2048   // d_inner
#define BV   4
#define TV   4096
#define MV   (BV * TV)   // 16384 rows for both GEMMs
#define GK   2048        // K for both GEMMs
#define NCH  64          // scan chunks
#define CH   64          // scan chunk length (NCH*CH == TV)

typedef __bf16 bf16x8 __attribute__((ext_vector_type(8)));
typedef __bf16 bf16x4 __attribute__((ext_vector_type(4)));
typedef float  floatx4 __attribute__((ext_vector_type(4)));

__device__ __forceinline__ void gload_lds16(const void* g, void* l) {
    __builtin_amdgcn_global_load_lds((const __attribute__((address_space(1))) void*)g,
                                     (__attribute__((address_space(3))) void*)l,
                                     16, 0, 0);
}

// ---------------- fused fp32 -> bf16 conversion (x, W_in, W_out) ----------
__global__ __launch_bounds__(256) void cvt_all(const float4* __restrict__ x,
                                               const float4* __restrict__ wi,
                                               const float4* __restrict__ wo,
                                               ushort4* __restrict__ xb,
                                               ushort4* __restrict__ wib,
                                               ushort4* __restrict__ wob) {
    int i = blockIdx.x * 256 + threadIdx.x;
    const float4* src;
    ushort4* dst;
    int off;
    if (i < 8388608)       { src = x;  dst = xb;  off = 0; }
    else if (i < 9437184)  { src = wi; dst = wib; off = 8388608; }
    else                   { src = wo; dst = wob; off = 9437184; }
    float4 v = src[i - off];
    __hip_bfloat16 a = __float2bfloat16(v.x);
    __hip_bfloat16 b = __float2bfloat16(v.y);
    __hip_bfloat16 c = __float2bfloat16(v.z);
    __hip_bfloat16 d = __float2bfloat16(v.w);
    ushort4 o;
    o.x = *(unsigned short*)&a;
    o.y = *(unsigned short*)&b;
    o.z = *(unsigned short*)&c;
    o.w = *(unsigned short*)&d;
    dst[i - off] = o;
}

// ---------------- bf16 GEMM, B-transposed, BK=64, two-panel LDS ----------
// C[m][n] = sum_k A[m][k] * Bt[n][k]; M=16384, N=2048, K=2048.
// 128x128 tile, BK=64 (halved barrier count vs BK=32), 4 waves (2x2),
// each wave 64x64 via 4x4 of 16x16x32 MFMA x 2 k-steps.
// LDS layout per matrix: [2 panels][128 rows][32 cols] bf16 — panel = K-half.
// Staging instr j (=wave*4+q): panel p=j&1, rows r0=(j>>1)*16 .. +16,
// lane l -> row r0+(l>>2), col p*32+(l&3)*8; LDS = p*8192B + r0*64B + l*16B
// (wave-uniform base + lane*16: satisfies global_load_lds constraint).
// Fragment reads keep 64B row stride -> 2-way bank aliasing (free).
// EPI==1: silu -> bf16 Cb. EPI==0: fp32 Cf.
template <int EPI>
__global__ __launch_bounds__(256) void gemm128_bt(const __hip_bfloat16* __restrict__ A,
                                                  const __hip_bfloat16* __restrict__ Bt,
                                                  float* __restrict__ Cf,
                                                  __hip_bfloat16* __restrict__ Cb) {
    __shared__ __align__(16) short As[2 * 128 * 32];
    __shared__ __align__(16) short Bs[2 * 128 * 32];

    const int tid  = threadIdx.x;
    const int lane = tid & 63;
    const int wave = tid >> 6;
    const int wm   = (wave >> 1) * 64;   // wave M offset in tile
    const int wn   = (wave & 1) * 64;    // wave N offset in tile
    const int lr   = lane & 15;          // row/col within 16-tile
    const int lq   = lane >> 4;          // quad

    // XCD-friendly swizzle: column-major within GROUP_M=8 m-tiles.
    const int num_n = gridDim.x;                       // 16
    const int p     = blockIdx.y * num_n + blockIdx.x; // linear id
    const int GM    = 8;
    const int grp   = p / (GM * num_n);
    const int rem   = p % (GM * num_n);
    const int m0    = (grp * GM + (rem % GM)) * 128;
    const int n0    = (rem / GM) * 128;

    // Precompute 4 staging (global offset, LDS dest) pairs per matrix.
    const __hip_bfloat16* Aps[4];
    const __hip_bfloat16* Bps[4];
    short* Ald[4];
    short* Bld[4];
#pragma unroll
    for (int q = 0; q < 4; ++q) {
        const int j    = wave * 4 + q;       // 0..15
        const int pan  = j & 1;
        const int r0   = (j >> 1) * 16;
        const int row  = r0 + (lane >> 2);
        const int col  = pan * 32 + (lane & 3) * 8;
        Aps[q] = A  + (size_t)(m0 + row) * GK + col;
        Bps[q] = Bt + (size_t)(n0 + row) * GK + col;
        Ald[q] = &As[pan * 4096 + r0 * 32 + lane * 8];
        Bld[q] = &Bs[pan * 4096 + r0 * 32 + lane * 8];
    }

    floatx4 acc[4][4];
#pragma unroll
    for (int i = 0; i < 4; ++i)
#pragma unroll
        for (int j = 0; j < 4; ++j) acc[i][j] = 0.f;

    for (int k0 = 0; k0 < GK; k0 += 64) {
#pragma unroll
        for (int q = 0; q < 4; ++q) {
            gload_lds16(Aps[q] + k0, Ald[q]);
            gload_lds16(Bps[q] + k0, Bld[q]);
        }
        __syncthreads();

#pragma unroll
        for (int s = 0; s < 2; ++s) {
            bf16x8 af[4], bfr[4];
#pragma unroll
            for (int i = 0; i < 4; ++i)
                af[i] = *(const bf16x8*)&As[s * 4096 + (wm + i * 16 + lr) * 32 + lq * 8];
#pragma unroll
            for (int j = 0; j < 4; ++j)
                bfr[j] = *(const bf16x8*)&Bs[s * 4096 + (wn + j * 16 + lr) * 32 + lq * 8];
#pragma unroll
            for (int i = 0; i < 4; ++i)
#pragma unroll
                for (int j = 0; j < 4; ++j)
                    acc[i][j] = __builtin_amdgcn_mfma_f32_16x16x32_bf16(af[i], bfr[j], acc[i][j], 0, 0, 0);
        }
        __syncthreads();
    }

    // Epilogue. C/D layout: col = lane&15, row = quad*4 + reg.
#pragma unroll
    for (int i = 0; i < 4; ++i) {
#pragma unroll
        for (int r = 0; r < 4; ++r) {
            const int row = m0 + wm + i * 16 + lq * 4 + r;
#pragma unroll
            for (int j = 0; j < 4; ++j) {
                const int col = n0 + wn + j * 16 + lr;
                float v = acc[i][j][r];
                if (EPI == 1) {
                    float s = v / (1.f + __expf(-v));   // silu
                    Cb[(size_t)row * DIV + col] = __float2bfloat16(s);
                } else {
                    Cf[(size_t)row * DIMV + col] = v;
                }
            }
        }
    }
}

// ---------------- scan pass 1: per-chunk carries (4 e-channels/thread) ----
__global__ __launch_bounds__(256) void scan_carry(const __hip_bfloat16* __restrict__ xp,
                                                  const float* __restrict__ logd,
                                                  const float* __restrict__ bias,
                                                  float* __restrict__ carry) {
    const int eg = blockIdx.x * 256 + threadIdx.x;  // e-group (4 channels)
    const int e0 = eg * 4;
    const int c = blockIdx.y;
    const int b = blockIdx.z;
    const float4 ld = ((const float4*)logd)[eg];
    const float4 bb = ((const float4*)bias)[eg];
    float dv[4] = {1.f / (1.f + __expf(-ld.x)), 1.f / (1.f + __expf(-ld.y)),
                   1.f / (1.f + __expf(-ld.z)), 1.f / (1.f + __expf(-ld.w))};
    float bv[4] = {bb.x, bb.y, bb.z, bb.w};
    const __hip_bfloat16* p = xp + ((size_t)(b * TV + c * CH)) * DIV + e0;
    float h[4] = {0.f, 0.f, 0.f, 0.f};
#pragma unroll 8
    for (int i = 0; i < CH; ++i) {
        bf16x4 v = *(const bf16x4*)(p + (size_t)i * DIV);
#pragma unroll
        for (int j = 0; j < 4; ++j)
            h[j] = dv[j] * ((float)v[j] + h[j]) + bv[j];
    }
    float4 o = {h[0], h[1], h[2], h[3]};
    *(float4*)&carry[((size_t)b * NCH + c) * DIV + e0] = o;
}

// ---------------- scan pass 2: combine carries, emit cell + h_final -------
__global__ __launch_bounds__(256) void scan_apply(const __hip_bfloat16* __restrict__ xp,
                                                  const float* __restrict__ logd,
                                                  const float* __restrict__ bias,
                                                  const float* __restrict__ h0,
                                                  const float* __restrict__ carry,
                                                  __hip_bfloat16* __restrict__ cell,
                                                  float* __restrict__ hfin) {
    const int eg = blockIdx.x * 256 + threadIdx.x;
    const int e0 = eg * 4;
    const int c = blockIdx.y;
    const int b = blockIdx.z;
    const float4 ld = ((const float4*)logd)[eg];
    const float4 bb = ((const float4*)bias)[eg];
    float dv[4] = {1.f / (1.f + __expf(-ld.x)), 1.f / (1.f + __expf(-ld.y)),
                   1.f / (1.f + __expf(-ld.z)), 1.f / (1.f + __expf(-ld.w))};
    float bv[4] = {bb.x, bb.y, bb.z, bb.w};
    float dCH[4];
#pragma unroll
    for (int j = 0; j < 4; ++j) dCH[j] = __powf(dv[j], (float)CH);

    // H = true h at entry to chunk c (chunk-level recurrence over carries)
    float4 H4 = *(const float4*)&h0[(size_t)b * DIV + e0];
    float H[4] = {H4.x, H4.y, H4.z, H4.w};
    for (int j = 0; j < c; ++j) {
        float4 cr = *(const float4*)&carry[((size_t)b * NCH + j) * DIV + e0];
#pragma unroll
        for (int q = 0; q < 4; ++q) H[q] = dCH[q] * H[q] + ((const float*)&cr)[q];
    }

    const size_t base = ((size_t)(b * TV + c * CH)) * DIV + e0;
    float h[4] = {H[0], H[1], H[2], H[3]};
#pragma unroll 4
    for (int i = 0; i < CH; ++i) {
        bf16x4 v = *(const bf16x4*)(xp + base + (size_t)i * DIV);
        ushort4 o;
        unsigned short* op = (unsigned short*)&o;
#pragma unroll
        for (int j = 0; j < 4; ++j) {
            h[j] = dv[j] * ((float)v[j] + h[j]) + bv[j];
            float cv = h[j] * (h[j] / (1.f + __expf(-h[j])));   // h * silu(h)
            __hip_bfloat16 cb = __float2bfloat16(cv);
            op[j] = *(unsigned short*)&cb;
        }
        *(ushort4*)(cell + base + (size_t)i * DIV) = o;
    }
    if (c == NCH - 1) {
        float4 o = {h[0], h[1], h[2], h[3]};
        *(float4*)&hfin[(size_t)b * DIV + e0] = o;
    }
}

// -------------------------------------------------------------------------
extern "C" void kernel_launch(void* const* d_in, const int* in_sizes, int n_in,
                              void* d_out, int out_size, void* d_ws, size_t ws_size,
                              hipStream_t stream) {
    const float* x     = (const float*)d_in[0];   // [B,T,DIM]
    const float* h0    = (const float*)d_in[1];   // [B,DI]
    const float* W_in  = (const float*)d_in[2];   // [DI,DIM]
    const float* W_out = (const float*)d_in[3];   // [DIM,DI]
    const float* log_d = (const float*)d_in[4];   // [DI]
    const float* bias  = (const float*)d_in[5];   // [DI]

    float* out  = (float*)d_out;                       // [B,T,DIM] fp32
    float* hfin = out + (size_t)BV * TV * DIMV;        // [B,DI] fp32

    // Workspace layout (bytes):
    char* ws = (char*)d_ws;
    __hip_bfloat16* xb    = (__hip_bfloat16*)ws;                          // 64 MiB
    __hip_bfloat16* cellb = xb;                                           // alias: x dead after GEMM1
    __hip_bfloat16* wib   = (__hip_bfloat16*)(ws + 67108864);             // 8 MiB
    __hip_bfloat16* wob   = (__hip_bfloat16*)(ws + 67108864 + 8388608);   // 8 MiB
    __hip_bfloat16* xpb   = (__hip_bfloat16*)(ws + 67108864 + 16777216);  // 64 MiB
    float*          carry = (float*)(ws + 134217728 + 16777216);          // 2 MiB

    // 1) convert inputs to bf16 (single fused kernel)
    {
        int n4 = 10485760;   // 8388608 + 1048576 + 1048576 float4s
        cvt_all<<<n4 / 256, 256, 0, stream>>>((const float4*)x, (const float4*)W_in,
                                              (const float4*)W_out,
                                              (ushort4*)xb, (ushort4*)wib, (ushort4*)wob);
    }

    // 2) GEMM1: xp = silu(x @ W_in^T), bf16 out
    gemm128_bt<1><<<dim3(DIV / 128, MV / 128), 256, 0, stream>>>(xb, wib, nullptr, xpb);

    // 3) scan: chunk carries, then combine + emit cell (bf16) and h_final
    scan_carry<<<dim3(DIV / 1024, NCH, BV), 256, 0, stream>>>(xpb, log_d, bias, carry);
    scan_apply<<<dim3(DIV / 1024, NCH, BV), 256, 0, stream>>>(xpb, log_d, bias, h0, carry, cellb, hfin);

    // 4) GEMM2: out = cell @ W_out^T, fp32 out
    gemm128_bt<0><<<dim3(DIMV / 128, MV / 128), 256, 0, stream>>>(cellb, wob, out, nullptr);
}